// Round 8
// baseline (5360.280 us; speedup 1.0000x reference)
//
#include <hip/hip_runtime.h>
#include <hip/hip_bf16.h>
#include <math.h>

#define STEPS 2048
#define BATCH 512
#define HBS 104   // hb per-column stride in floats (416 B: 16B-aligned, bank-offset 8)

typedef __attribute__((ext_vector_type(8))) short short8;
typedef __attribute__((ext_vector_type(4))) short short4v;
typedef __attribute__((ext_vector_type(2))) short short2v;
typedef __attribute__((ext_vector_type(4))) float f32x4;

__device__ __forceinline__ short f2bf(float f) {
    union { float f; unsigned u; } v; v.f = f;
    unsigned u = v.u;
    return (short)((u + 0x7FFFu + ((u >> 16) & 1u)) >> 16);  // RNE
}
__device__ __forceinline__ short2v pk2(float a, float b) {
    __hip_bfloat162 h = __float22bfloat162_rn(make_float2(a, b));
    union { __hip_bfloat162 h; short2v s; } u; u.h = h; return u.s;
}

// ---------------------------------------------------------------------------
// baseflow[b] = 25th percentile (linear interp) of flow[:, b]
// ---------------------------------------------------------------------------
__global__ __launch_bounds__(256) void baseflow_kernel(
    const float* __restrict__ hyd, float* __restrict__ bf)
{
    __shared__ float arr[STEPS];
    const int b = blockIdx.x;
    const int tid = threadIdx.x;
    for (int t = tid; t < STEPS; t += 256)
        arr[t] = hyd[(size_t)(t * BATCH + b) * 17];
    __syncthreads();
    for (int k = 2; k <= STEPS; k <<= 1) {
        for (int j = k >> 1; j > 0; j >>= 1) {
            for (int i = tid; i < STEPS; i += 256) {
                int ixj = i ^ j;
                if (ixj > i) {
                    float a = arr[i], c = arr[ixj];
                    bool up = ((i & k) == 0);
                    if (up ? (a > c) : (a < c)) { arr[i] = c; arr[ixj] = a; }
                }
            }
            __syncthreads();
        }
    }
    if (tid == 0) bf[b] = arr[511] + 0.75f * (arr[512] - arr[511]);
}

// ---------------------------------------------------------------------------
// 256 blocks x 256 threads (4 waves), 2 batch columns per block, 1 block/CU.
// WAVE-SPECIALIZED chain: wave 0 owns the serial recurrence (tail + full
// redundant L0, 8 MFMAs, W0aug with 0.01-fold + b0 at k=24); waves 1-3 own
// the 6 head tiles + transcendental epilogue; all 4 waves share L1.
// Per step: B1 (h1F) -> L1 -> B2 (h2F) -> heads -> B3 (hb) -> wave0 tail+L0.
// Tail LDS traffic: 23 ds_read_b128 TOTAL per step (was 92).
// x/rain prefetched global->register by wave 0 at the top of its segment.
// ---------------------------------------------------------------------------
__global__ __launch_bounds__(256, 1) void hyd_step_kernel(
    const float* __restrict__ hyd,
    const float* __restrict__ W0,  const float* __restrict__ b0,
    const float* __restrict__ W1,  const float* __restrict__ b1,
    const float* __restrict__ Win, const float* __restrict__ bin,
    const float* __restrict__ Wout,const float* __restrict__ bout,
    const float* __restrict__ baseflow,
    float* __restrict__ out)
{
    __shared__ __align__(16) short h1F[256 * 8];   // frag-major h1 (all 8 M-tiles)
    __shared__ __align__(16) short h2F[256 * 8];   // frag-major h2
    __shared__ __align__(16) float hb[2 * HBS];    // [col*HBS + m]; m<9 exp, else sigmoid

    const int tid  = threadIdx.x;
    const int blk  = blockIdx.x;
    const int lane = tid & 63;
    const int wv   = tid >> 6;
    const int cn   = lane & 15;
    const int cg   = lane >> 4;
    const int col  = lane & 1;

    for (int i = tid; i < 256 * 8; i += 256) { h1F[i] = 0; h2F[i] = 0; }

    // ---- L1 A-frags + bias (all waves: 2 M-tiles each) ----
    short8 a1[2][4]; f32x4 c1[2];
    #pragma unroll
    for (int i = 0; i < 2; ++i) {
        const int row = (2 * wv + i) * 16 + cn;
        #pragma unroll
        for (int kt = 0; kt < 4; ++kt)
            #pragma unroll
            for (int j = 0; j < 8; ++j)
                a1[i][kt][j] = f2bf(W1[row * 128 + kt * 32 + cg * 8 + j]);
        #pragma unroll
        for (int r = 0; r < 4; ++r)
            c1[i][r] = b1[(2 * wv + i) * 16 + cg * 4 + r];
    }

    // ---- head A-frags (waves 1..3: 2 tiles each) ----
    short8 ah[2][4]; f32x4 ch[2];
    if (wv >= 1) {
        #pragma unroll
        for (int i = 0; i < 2; ++i) {
            const int ht = (wv - 1) * 2 + i;
            const int row = ht * 16 + cn;
            #pragma unroll
            for (int kt = 0; kt < 4; ++kt)
                #pragma unroll
                for (int j = 0; j < 8; ++j) {
                    const int k = kt * 32 + cg * 8 + j;
                    float w = 0.f;
                    if (row < 9)       w = Win[row * 128 + k];
                    else if (row < 89) w = Wout[(row - 9) * 128 + k];
                    ah[i][kt][j] = f2bf(w);
                }
            #pragma unroll
            for (int r = 0; r < 4; ++r) {
                const int m = ht * 16 + cg * 4 + r;
                float bb = 0.f;
                if (m < 9)       bb = bin[m];
                else if (m < 89) bb = bout[m - 9];
                ch[i][r] = bb;
            }
        }
    }

    // ---- wave 0: W0aug A-frags + recurrent state ----
    short8 a0[8];
    float sreg[8];
    short8 sp, onef = (short8)0;
    float bfv = 0.f, rainC = 0.f;
    const bool xact = (cg < 2 && cn < 2);
    const float* xbase = hyd + (size_t)(blk * 2 + cn) * 17 + 1;
    const float* rbase = hyd + (size_t)(blk * 2 + col) * 17 + 1;
    if (wv == 0) {
        #pragma unroll
        for (int mt = 0; mt < 8; ++mt) {
            const int row = mt * 16 + cn;
            #pragma unroll
            for (int j = 0; j < 8; ++j) {
                const int k = cg * 8 + j;
                float w;
                if (k < 16)       w = W0[row * 24 + k];
                else if (k < 24)  w = 0.01f * W0[row * 24 + k];
                else if (k == 24) w = b0[row];
                else              w = 0.f;
                a0[mt][j] = f2bf(w);
            }
        }
        #pragma unroll
        for (int j = 0; j < 8; ++j) sreg[j] = (j == 1) ? 1.f : 0.f;
        #pragma unroll
        for (int jj = 0; jj < 4; ++jj) {
            short2v p = pk2(sreg[2 * jj], sreg[2 * jj + 1]);
            sp[2 * jj] = p[0]; sp[2 * jj + 1] = p[1];
        }
        onef[0] = (short)0x3F80;       // B[24][n] = 1.0 (bias slot)
        bfv = baseflow[blk * 2 + col];
        rainC = rbase[0];
    }
    __syncthreads();   // zero-init + preload complete

    // ---- wave 0: initial L0(0) ----
    if (wv == 0) {
        float x0[8];
        #pragma unroll
        for (int j = 0; j < 8; ++j) x0[j] = xact ? xbase[cg * 8 + j] : 0.f;
        short8 xq;
        #pragma unroll
        for (int jj = 0; jj < 4; ++jj) {
            short2v p = pk2(x0[2 * jj], x0[2 * jj + 1]);
            xq[2 * jj] = p[0]; xq[2 * jj + 1] = p[1];
        }
        short8 bf0 = (cg < 2) ? xq : ((cg == 2) ? sp : onef);
        #pragma unroll
        for (int mt = 0; mt < 8; ++mt) {
            f32x4 z = {0.f, 0.f, 0.f, 0.f};
            f32x4 acc = __builtin_amdgcn_mfma_f32_16x16x32_bf16(a0[mt], bf0, z, 0, 0, 0);
            if (cn < 2) {
                const int m0 = mt * 16 + cg * 4;
                short4v p;
                short2v pa = pk2(fmaxf(acc[0], 0.f), fmaxf(acc[1], 0.f));
                short2v pb = pk2(fmaxf(acc[2], 0.f), fmaxf(acc[3], 0.f));
                p[0] = pa[0]; p[1] = pa[1]; p[2] = pb[0]; p[3] = pb[1];
                *(short4v*)&h1F[((m0 >> 3) * 16 + cn) * 8 + (m0 & 7)] = p;
            }
        }
    }

    #pragma unroll 1
    for (int t = 0; t < STEPS; ++t) {
        __syncthreads();   // B1: h1F(t) ready

        // === L1: 2 M-tiles per wave ===
        short8 bh1[4];
        #pragma unroll
        for (int kt = 0; kt < 4; ++kt)
            bh1[kt] = *(const short8*)&h1F[(kt * 64 + lane) * 8];
        #pragma unroll
        for (int i = 0; i < 2; ++i) {
            f32x4 acc = c1[i];
            #pragma unroll
            for (int kt = 0; kt < 4; ++kt)
                acc = __builtin_amdgcn_mfma_f32_16x16x32_bf16(a1[i][kt], bh1[kt], acc, 0, 0, 0);
            if (cn < 2) {
                const int m0 = (2 * wv + i) * 16 + cg * 4;
                short4v p;
                short2v pa = pk2(fmaxf(acc[0], 0.f), fmaxf(acc[1], 0.f));
                short2v pb = pk2(fmaxf(acc[2], 0.f), fmaxf(acc[3], 0.f));
                p[0] = pa[0]; p[1] = pa[1]; p[2] = pb[0]; p[3] = pb[1];
                *(short4v*)&h2F[((m0 >> 3) * 16 + cn) * 8 + (m0 & 7)] = p;
            }
        }
        __syncthreads();   // B2: h2F(t) ready

        // === heads on waves 1..3: exp(logits) m<9, sigmoid(gates) m>=9 ===
        if (wv >= 1) {
            short8 bh2[4];
            #pragma unroll
            for (int kt = 0; kt < 4; ++kt)
                bh2[kt] = *(const short8*)&h2F[(kt * 64 + lane) * 8];
            #pragma unroll
            for (int i = 0; i < 2; ++i) {
                f32x4 acc = ch[i];
                #pragma unroll
                for (int kt = 0; kt < 4; ++kt)
                    acc = __builtin_amdgcn_mfma_f32_16x16x32_bf16(ah[i][kt], bh2[kt], acc, 0, 0, 0);
                if (cn < 2) {
                    const int ht = (wv - 1) * 2 + i;
                    float4 o;
                    #pragma unroll
                    for (int r = 0; r < 4; ++r) {
                        const int m = ht * 16 + cg * 4 + r;
                        const float v = acc[r];
                        const bool isl = (m < 9);
                        const float em = __expf(isl ? v : -v);
                        ((float*)&o)[r] = isl ? em : __builtin_amdgcn_rcpf(1.f + em);
                    }
                    *(float4*)&hb[cn * HBS + ht * 16 + cg * 4] = o;
                }
            }
        }
        __syncthreads();   // B3: hb(t) ready

        // === wave 0: prefetch x/rain(t+1), tail(t), L0(t+1) ===
        if (wv == 0) {
            const size_t off = (size_t)((t + 1 < STEPS) ? (t + 1) : t) * (BATCH * 17);
            float nx[8];
            #pragma unroll
            for (int j = 0; j < 8; ++j) nx[j] = xact ? xbase[off + cg * 8 + j] : 0.f;
            const float nrain = rbase[off];

            // ---- tail (per-lane redundant within wave 0, col = lane&1) ----
            float gv[92];
            const float4* hp = (const float4*)&hb[col * HBS];
            #pragma unroll
            for (int c2 = 0; c2 < 23; ++c2)
                ((float4*)gv)[c2] = hp[c2];

            float den = ((gv[0] + gv[1]) + (gv[2] + gv[3])) +
                        ((gv[4] + gv[5]) + (gv[6] + gv[7])) + gv[8];
            float rr = rainC * __builtin_amdgcn_rcpf(den);
            #pragma unroll
            for (int j = 0; j < 8; ++j) sreg[j] += gv[1 + j] * rr;

            #pragma unroll
            for (int d = 0; d < 8; ++d) {
                float fb[8];
                #pragma unroll
                for (int j = 0; j < 8; ++j) fb[j] = gv[9 + d * 8 + j] * sreg[j];
                float fs = ((fb[0] + fb[1]) + (fb[2] + fb[3])) +
                           ((fb[4] + fb[5]) + (fb[6] + fb[7]));
                #pragma unroll
                for (int j = 0; j < 8; ++j) sreg[j] -= fb[j];
                sreg[d] += fs;
            }
            #pragma unroll
            for (int j = 0; j < 8; ++j) sreg[j] -= gv[73 + j] * sreg[j];   // escape
            float fd[8];
            #pragma unroll
            for (int j = 0; j < 8; ++j) fd[j] = gv[81 + j] * sreg[j];      // flow
            float fsum = ((fd[0] + fd[1]) + (fd[2] + fd[3])) +
                         ((fd[4] + fd[5]) + (fd[6] + fd[7]));
            #pragma unroll
            for (int j = 0; j < 8; ++j) sreg[j] -= fd[j];
            if (t == 0) sreg[2] = bfv / fmaxf(gv[83], 1e-5f);   // b_flow[SLOW=2]

            if (lane < 2) out[(size_t)t * BATCH + blk * 2 + lane] = fsum;

            #pragma unroll
            for (int jj = 0; jj < 4; ++jj) {
                short2v p = pk2(sreg[2 * jj], sreg[2 * jj + 1]);
                sp[2 * jj] = p[0]; sp[2 * jj + 1] = p[1];
            }

            // ---- L0(t+1): 8 redundant MFMAs ----
            short8 xq;
            #pragma unroll
            for (int jj = 0; jj < 4; ++jj) {
                short2v p = pk2(nx[2 * jj], nx[2 * jj + 1]);
                xq[2 * jj] = p[0]; xq[2 * jj + 1] = p[1];
            }
            short8 bf0 = (cg < 2) ? xq : ((cg == 2) ? sp : onef);
            #pragma unroll
            for (int mt = 0; mt < 8; ++mt) {
                f32x4 z = {0.f, 0.f, 0.f, 0.f};
                f32x4 acc = __builtin_amdgcn_mfma_f32_16x16x32_bf16(a0[mt], bf0, z, 0, 0, 0);
                if (cn < 2) {
                    const int m0 = mt * 16 + cg * 4;
                    short4v p;
                    short2v pa = pk2(fmaxf(acc[0], 0.f), fmaxf(acc[1], 0.f));
                    short2v pb = pk2(fmaxf(acc[2], 0.f), fmaxf(acc[3], 0.f));
                    p[0] = pa[0]; p[1] = pa[1]; p[2] = pb[0]; p[3] = pb[1];
                    *(short4v*)&h1F[((m0 >> 3) * 16 + cn) * 8 + (m0 & 7)] = p;
                }
            }
            rainC = nrain;
        }
        // WAR safety: h1F(t+1) writes (wave0, after B3) vs h1F(t) reads
        // (all waves, before B2) — ordered by B2/B3. h2F(t+1) writes after
        // B1(t+1) vs h2F(t) reads before B3(t) — ordered. hb(t+1) writes
        // after B2(t+1) vs hb(t) reads before B1(t+1) — ordered.
    }
}

// ---------------------------------------------------------------------------
extern "C" void kernel_launch(void* const* d_in, const int* in_sizes, int n_in,
                              void* d_out, int out_size, void* d_ws, size_t ws_size,
                              hipStream_t stream)
{
    const float* hyd  = (const float*)d_in[0];
    const float* W0   = (const float*)d_in[1];
    const float* b0   = (const float*)d_in[2];
    const float* W1   = (const float*)d_in[3];
    const float* b1   = (const float*)d_in[4];
    const float* Win  = (const float*)d_in[5];
    const float* bin  = (const float*)d_in[6];
    const float* Wout = (const float*)d_in[7];
    const float* bout = (const float*)d_in[8];
    float* out = (float*)d_out;
    float* bf  = (float*)d_ws;

    baseflow_kernel<<<BATCH, 256, 0, stream>>>(hyd, bf);
    hyd_step_kernel<<<BATCH / 2, 256, 0, stream>>>(
        hyd, W0, b0, W1, b1, Win, bin, Wout, bout, bf, out);
}

// Round 9
// 3480.612 us; speedup vs baseline: 1.5400x; 1.5400x over previous
//
#include <hip/hip_runtime.h>
#include <hip/hip_bf16.h>
#include <math.h>

#define STEPS 2048
#define BATCH 512

typedef __attribute__((ext_vector_type(8))) short short8;
typedef __attribute__((ext_vector_type(4))) short short4v;
typedef __attribute__((ext_vector_type(2))) short short2v;
typedef __attribute__((ext_vector_type(4))) float f32x4;

__device__ __forceinline__ short f2bf(float f) {
    union { float f; unsigned u; } v; v.f = f;
    unsigned u = v.u;
    return (short)((u + 0x7FFFu + ((u >> 16) & 1u)) >> 16);  // RNE
}
__device__ __forceinline__ short2v pk2(float a, float b) {
    __hip_bfloat162 h = __float22bfloat162_rn(make_float2(a, b));
    union { __hip_bfloat162 h; short2v s; } u; u.h = h; return u.s;
}

// ---------------------------------------------------------------------------
// baseflow[b] = 25th percentile (linear interp) of flow[:, b]
// ---------------------------------------------------------------------------
__global__ __launch_bounds__(256) void baseflow_kernel(
    const float* __restrict__ hyd, float* __restrict__ bf)
{
    __shared__ float arr[STEPS];
    const int b = blockIdx.x;
    const int tid = threadIdx.x;
    for (int t = tid; t < STEPS; t += 256)
        arr[t] = hyd[(size_t)(t * BATCH + b) * 17];
    __syncthreads();
    for (int k = 2; k <= STEPS; k <<= 1) {
        for (int j = k >> 1; j > 0; j >>= 1) {
            for (int i = tid; i < STEPS; i += 256) {
                int ixj = i ^ j;
                if (ixj > i) {
                    float a = arr[i], c = arr[ixj];
                    bool up = ((i & k) == 0);
                    if (up ? (a > c) : (a < c)) { arr[i] = c; arr[ixj] = a; }
                }
            }
            __syncthreads();
        }
    }
    if (tid == 0) bf[b] = arr[511] + 0.75f * (arr[512] - arr[511]);
}

// ---------------------------------------------------------------------------
// R4 skeleton (proven best: all waves symmetric, 3 barriers/step, LDS ring,
// per-lane redundant register tail) + three drain/latency fixes:
//  (1) out[] staged in LDS, flushed once per 16-step group by wave 0
//      -> no per-step vmcnt(0) store-drain at B1
//  (2) ring double-buffered through registers: group g+1's global loads are
//      issued right after the group-top barrier, written to LDS 16 steps
//      later -> no load-drain at the group barrier
//  (3) K=128 MFMA chains split into 2 independent halves + f32x4 add
// ---------------------------------------------------------------------------
__global__ __launch_bounds__(256, 1) void hyd_step_kernel(
    const float* __restrict__ hyd,
    const float* __restrict__ W0,  const float* __restrict__ b0,
    const float* __restrict__ W1,  const float* __restrict__ b1,
    const float* __restrict__ Win, const float* __restrict__ bin,
    const float* __restrict__ Wout,const float* __restrict__ bout,
    const float* __restrict__ baseflow,
    float* __restrict__ out)
{
    __shared__ __align__(16) short h1F[256 * 8];
    __shared__ __align__(16) short h2F[256 * 8];
    __shared__ __align__(16) short ringX[16 * 4 * 8];  // [slot][g2*2+col][j]
    __shared__ float ringR[16][2];                     // rain (hyd[...,1])
    __shared__ __align__(16) float hb[2][96];          // m<9: exp(logit); else sigmoid
    __shared__ float outS[16][2];                      // staged flow outputs

    const int tid  = threadIdx.x;
    const int blk  = blockIdx.x;
    const int lane = tid & 63;
    const int wv   = tid >> 6;
    const int cn   = lane & 15;
    const int cg   = lane >> 4;
    const int col  = lane & 1;    // tail column owned by this lane

    for (int i = tid; i < 256 * 8; i += 256) { h1F[i] = 0; h2F[i] = 0; }

    // ---- weight A-fragments + bias C-inits (one-time) ----
    short8 a0[2]; f32x4 c0[2];
    short8 a1[2][4]; f32x4 c1[2];
    short8 ah[2][4]; f32x4 ch[2];
    #pragma unroll
    for (int i = 0; i < 2; ++i) {
        const int mt = 2 * wv + i;
        const int row = mt * 16 + cn;
        #pragma unroll
        for (int j = 0; j < 8; ++j) {
            int k = cg * 8 + j;
            a0[i][j] = (k < 24) ? f2bf(W0[row * 24 + k]) : (short)0;
        }
        #pragma unroll
        for (int kt = 0; kt < 4; ++kt)
            #pragma unroll
            for (int j = 0; j < 8; ++j)
                a1[i][kt][j] = f2bf(W1[row * 128 + kt * 32 + cg * 8 + j]);
        #pragma unroll
        for (int r = 0; r < 4; ++r) {
            int m = mt * 16 + cg * 4 + r;
            c0[i][r] = b0[m];
            c1[i][r] = b1[m];
        }
    }
    const int nht = (wv < 2) ? 2 : 1;
    int htile[2];
    htile[0] = (wv < 2) ? 2 * wv : 4 + (wv - 2);
    htile[1] = (wv < 2) ? 2 * wv + 1 : htile[0];
    #pragma unroll
    for (int i = 0; i < 2; ++i) {
        const int ht = htile[i];
        const int row = ht * 16 + cn;
        #pragma unroll
        for (int kt = 0; kt < 4; ++kt)
            #pragma unroll
            for (int j = 0; j < 8; ++j) {
                int k = kt * 32 + cg * 8 + j;
                float w = 0.f;
                if (row < 9)       w = Win[row * 128 + k];
                else if (row < 89) w = Wout[(row - 9) * 128 + k];
                ah[i][kt][j] = f2bf(w);
            }
        #pragma unroll
        for (int r = 0; r < 4; ++r) {
            int m = ht * 16 + cg * 4 + r;
            float bb = 0.f;
            if (m < 9)       bb = bin[m];
            else if (m < 89) bb = bout[m - 9];
            ch[i][r] = bb;
        }
    }

    // ---- recurrent state, replicated per lane for column col ----
    float sreg[8];
    #pragma unroll
    for (int j = 0; j < 8; ++j) sreg[j] = (j == 1) ? 1.f : 0.f;
    const float bfv = baseflow[blk * 2 + col];
    short8 spack;
    #pragma unroll
    for (int jj = 0; jj < 4; ++jj) {
        short2v p = pk2(0.01f * sreg[2 * jj], 0.01f * sreg[2 * jj + 1]);
        spack[2 * jj] = p[0]; spack[2 * jj + 1] = p[1];
    }

    // ---- ring prefetch registers: group 0 loaded in prologue ----
    const int rtp = tid >> 2, rc = (tid >> 1) & 1, rg2 = tid & 1;  // tid<64 map
    const int rl  = tid - 64, rtpR = rl >> 1, rcR = rl & 1;        // tid<96 map
    float xr[8];
    #pragma unroll
    for (int j = 0; j < 8; ++j) xr[j] = 0.f;
    float rr = 0.f;
    if (tid < 64) {
        const float* p = hyd + ((size_t)rtp * BATCH + blk * 2 + rc) * 17 + 1 + rg2 * 8;
        #pragma unroll
        for (int j = 0; j < 8; ++j) xr[j] = p[j];
    } else if (tid < 96) {
        rr = hyd[((size_t)rtpR * BATCH + blk * 2 + rcR) * 17 + 1];
    }

    for (int tb = 0; tb < STEPS; tb += 16) {
        // ---- publish prefetched group into the LDS ring ----
        if (tid < 64) {
            short8 w;
            short2v q0 = pk2(xr[0], xr[1]), q1 = pk2(xr[2], xr[3]);
            short2v q2 = pk2(xr[4], xr[5]), q3 = pk2(xr[6], xr[7]);
            w[0] = q0[0]; w[1] = q0[1]; w[2] = q1[0]; w[3] = q1[1];
            w[4] = q2[0]; w[5] = q2[1]; w[6] = q3[0]; w[7] = q3[1];
            *(short8*)&ringX[(rtp * 4 + rg2 * 2 + rc) * 8] = w;
        } else if (tid < 96) {
            ringR[rtpR][rcR] = rr;
        }
        __syncthreads();   // ring published (drains last group's flush stores)

        // ---- issue NEXT group's loads (consumed 16 steps from now) ----
        {
            const int ntb = (tb + 16 < STEPS) ? (tb + 16) : tb;
            if (tid < 64) {
                const float* p = hyd + ((size_t)(ntb + rtp) * BATCH + blk * 2 + rc) * 17 + 1 + rg2 * 8;
                #pragma unroll
                for (int j = 0; j < 8; ++j) xr[j] = p[j];
            } else if (tid < 96) {
                rr = hyd[((size_t)(ntb + rtpR) * BATCH + blk * 2 + rcR) * 17 + 1];
            }
        }

        for (int tt = 0; tt < 16; ++tt) {
            const int t = tb + tt;

            // rain — read BEFORE B1 so next group's ring write can't race
            const float rain = ringR[tt][col];

            // === L0: h1 = relu(W0 @ [x, 0.01*stores] + b0) ===
            short8 bfrag = (short8)0;
            if (cn < 2) {
                if (cg < 2)        bfrag = *(const short8*)&ringX[(tt * 4 + cg * 2 + cn) * 8];
                else if (cg == 2)  bfrag = spack;
            }
            #pragma unroll
            for (int i = 0; i < 2; ++i) {
                f32x4 acc = __builtin_amdgcn_mfma_f32_16x16x32_bf16(a0[i], bfrag, c0[i], 0, 0, 0);
                if (cn < 2) {
                    int m0 = (2 * wv + i) * 16 + cg * 4;
                    short4v p;
                    short2v pa = pk2(fmaxf(acc[0], 0.f), fmaxf(acc[1], 0.f));
                    short2v pb = pk2(fmaxf(acc[2], 0.f), fmaxf(acc[3], 0.f));
                    p[0] = pa[0]; p[1] = pa[1]; p[2] = pb[0]; p[3] = pb[1];
                    *(short4v*)&h1F[((m0 >> 3) * 16 + cn) * 8 + (m0 & 7)] = p;
                }
            }
            __syncthreads();   // B1

            // === L1: h2 = relu(W1 @ h1 + b1), split 2+2 accumulation ===
            short8 bf1[4];
            #pragma unroll
            for (int kt = 0; kt < 4; ++kt)
                bf1[kt] = *(const short8*)&h1F[(kt * 64 + lane) * 8];
            #pragma unroll
            for (int i = 0; i < 2; ++i) {
                f32x4 z = {0.f, 0.f, 0.f, 0.f};
                f32x4 aA = __builtin_amdgcn_mfma_f32_16x16x32_bf16(a1[i][0], bf1[0], c1[i], 0, 0, 0);
                aA = __builtin_amdgcn_mfma_f32_16x16x32_bf16(a1[i][1], bf1[1], aA, 0, 0, 0);
                f32x4 aB = __builtin_amdgcn_mfma_f32_16x16x32_bf16(a1[i][2], bf1[2], z, 0, 0, 0);
                aB = __builtin_amdgcn_mfma_f32_16x16x32_bf16(a1[i][3], bf1[3], aB, 0, 0, 0);
                f32x4 acc = aA + aB;
                if (cn < 2) {
                    int m0 = (2 * wv + i) * 16 + cg * 4;
                    short4v p;
                    short2v pa = pk2(fmaxf(acc[0], 0.f), fmaxf(acc[1], 0.f));
                    short2v pb = pk2(fmaxf(acc[2], 0.f), fmaxf(acc[3], 0.f));
                    p[0] = pa[0]; p[1] = pa[1]; p[2] = pb[0]; p[3] = pb[1];
                    *(short4v*)&h2F[((m0 >> 3) * 16 + cn) * 8 + (m0 & 7)] = p;
                }
            }
            __syncthreads();   // B2

            // === heads: exp(logits) m<9, sigmoid(gates) m>=9 ===
            short8 bf2[4];
            #pragma unroll
            for (int kt = 0; kt < 4; ++kt)
                bf2[kt] = *(const short8*)&h2F[(kt * 64 + lane) * 8];
            #pragma unroll
            for (int i = 0; i < 2; ++i) {
                if (i < nht) {
                    f32x4 z = {0.f, 0.f, 0.f, 0.f};
                    f32x4 aA = __builtin_amdgcn_mfma_f32_16x16x32_bf16(ah[i][0], bf2[0], ch[i], 0, 0, 0);
                    aA = __builtin_amdgcn_mfma_f32_16x16x32_bf16(ah[i][1], bf2[1], aA, 0, 0, 0);
                    f32x4 aB = __builtin_amdgcn_mfma_f32_16x16x32_bf16(ah[i][2], bf2[2], z, 0, 0, 0);
                    aB = __builtin_amdgcn_mfma_f32_16x16x32_bf16(ah[i][3], bf2[3], aB, 0, 0, 0);
                    f32x4 acc = aA + aB;
                    if (cn < 2) {
                        const int ht = htile[i];
                        float4 o;
                        #pragma unroll
                        for (int r = 0; r < 4; ++r) {
                            int m = ht * 16 + cg * 4 + r;
                            float v = acc[r];
                            bool isl = (m < 9);
                            float em = __expf(isl ? v : -v);
                            ((float*)&o)[r] = isl ? em : __builtin_amdgcn_rcpf(1.f + em);
                        }
                        *(float4*)&hb[cn][ht * 16 + cg * 4] = o;
                    }
                }
            }
            __syncthreads();   // B3

            // === tail: redundant on every lane, all in registers ===
            {
                float gv[92];
                const float4* hp = (const float4*)&hb[col][0];
                #pragma unroll
                for (int c2 = 0; c2 < 23; ++c2)
                    ((float4*)gv)[c2] = hp[c2];

                float den = ((gv[0] + gv[1]) + (gv[2] + gv[3])) +
                            ((gv[4] + gv[5]) + (gv[6] + gv[7])) + gv[8];
                float rr2 = rain * __builtin_amdgcn_rcpf(den);
                #pragma unroll
                for (int j = 0; j < 8; ++j) sreg[j] += gv[1 + j] * rr2;

                #pragma unroll
                for (int d = 0; d < 8; ++d) {
                    float fb[8];
                    #pragma unroll
                    for (int j = 0; j < 8; ++j) fb[j] = gv[9 + d * 8 + j] * sreg[j];
                    float fs = ((fb[0] + fb[1]) + (fb[2] + fb[3])) +
                               ((fb[4] + fb[5]) + (fb[6] + fb[7]));
                    #pragma unroll
                    for (int j = 0; j < 8; ++j) sreg[j] -= fb[j];
                    sreg[d] += fs;
                }
                #pragma unroll
                for (int j = 0; j < 8; ++j) sreg[j] -= gv[73 + j] * sreg[j];   // escape
                float fd[8];
                #pragma unroll
                for (int j = 0; j < 8; ++j) fd[j] = gv[81 + j] * sreg[j];      // flow
                float fsum = ((fd[0] + fd[1]) + (fd[2] + fd[3])) +
                             ((fd[4] + fd[5]) + (fd[6] + fd[7]));
                #pragma unroll
                for (int j = 0; j < 8; ++j) sreg[j] -= fd[j];
                if (t == 0) sreg[2] = bfv / fmaxf(gv[83], 1e-5f);   // b_flow[SLOW]

                // stage output in LDS (no global store => no vmcnt drain at B1)
                if (tid < 2) outS[tt][tid] = fsum;

                #pragma unroll
                for (int jj = 0; jj < 4; ++jj) {
                    short2v p = pk2(0.01f * sreg[2 * jj], 0.01f * sreg[2 * jj + 1]);
                    spack[2 * jj] = p[0]; spack[2 * jj + 1] = p[1];
                }
            }
            // no B4: stores live in registers; h1F(t+1) writes are ordered
            // after every wave's h1F(t) reads by B2(t)/B3(t)
        }

        // ---- flush staged outputs (wave 0 only — same-wave LDS visibility;
        //      store drain merges with the next group-top barrier) ----
        if (tid < 32) {
            const int tp = tid >> 1, c = tid & 1;
            out[(size_t)(tb + tp) * BATCH + blk * 2 + c] = outS[tp][c];
        }
    }
}

// ---------------------------------------------------------------------------
extern "C" void kernel_launch(void* const* d_in, const int* in_sizes, int n_in,
                              void* d_out, int out_size, void* d_ws, size_t ws_size,
                              hipStream_t stream)
{
    const float* hyd  = (const float*)d_in[0];
    const float* W0   = (const float*)d_in[1];
    const float* b0   = (const float*)d_in[2];
    const float* W1   = (const float*)d_in[3];
    const float* b1   = (const float*)d_in[4];
    const float* Win  = (const float*)d_in[5];
    const float* bin  = (const float*)d_in[6];
    const float* Wout = (const float*)d_in[7];
    const float* bout = (const float*)d_in[8];
    float* out = (float*)d_out;
    float* bf  = (float*)d_ws;

    baseflow_kernel<<<BATCH, 256, 0, stream>>>(hyd, bf);
    hyd_step_kernel<<<BATCH / 2, 256, 0, stream>>>(
        hyd, W0, b0, W1, b1, Win, bin, Wout, bout, bf, out);
}